// Round 16
// baseline (16450.441 us; speedup 1.0000x reference)
//
#include <hip/hip_runtime.h>
#include <math.h>
#include <float.h>

#define KE 8192        // number of edges
#define NPF 3072       // floats per edge (1024 * 3)
#define NT 512         // threads in chain kernel (8 waves, 2 per SIMD)
#define EPT 16         // edges per thread in phase 0
#define NW  8          // waves
#define TOPK_N 10
#define KNN 16         // candidate list length

typedef unsigned long long u64;
typedef float v2f __attribute__((ext_vector_type(2)));

#define GETP(arr, k) (((k) & 1) ? arr[(k) >> 1].y : arr[(k) >> 1].x)

#define DPPMIN(x, ctrl, rmask)                                              \
  do {                                                                      \
    unsigned _t = (unsigned)__builtin_amdgcn_update_dpp(                    \
        (int)0xFFFFFFFF, (int)(x), (ctrl), (rmask), 0xf, false);            \
    (x) = ((x) < _t) ? (x) : _t;                                            \
  } while (0)

// numpy-exact squared distance (no contraction) for DISCRETE decisions
__device__ __forceinline__ float dist2(float ax, float ay, float az,
                                       float bx, float by, float bz) {
#pragma clang fp contract(off)
  float dx = ax - bx, dy = ay - by, dz = az - bz;
  float s = (dx * dx + dy * dy) + dz * dz;
  return s;
}

// packed 2-edge squared distance, FMA form (argmin-safe; certified by bench)
__device__ __forceinline__ v2f dist2p(v2f cx, v2f cy, v2f cz,
                                      v2f px, v2f py, v2f pz) {
  v2f dx = px - cx, dy = py - cy, dz = pz - cz;
  return __builtin_elementwise_fma(dx, dx,
           __builtin_elementwise_fma(dy, dy, dz * dz));
}

// scalar twin of dist2p: IDENTICAL dataflow -> bitwise-identical values
__device__ __forceinline__ float dist2f(float cx, float cy, float cz,
                                        float px, float py, float pz) {
  float dx = px - cx, dy = py - cy, dz = pz - cz;
  return fmaf(dx, dx, fmaf(dy, dy, dz * dz));
}

__device__ __forceinline__ float dist3(float ax, float ay, float az,
                                       float bx, float by, float bz) {
  return sqrtf(dist2(ax, ay, az, bx, by, bz));
}

__device__ __forceinline__ u64 umin64(u64 a, u64 b) { return a < b ? a : b; }

// ---- build the compact 32B/edge endpoint table ----
extern "C" __global__ void __launch_bounds__(256)
tbl_build_kernel(const float* __restrict__ edges, float4* __restrict__ tbl4)
{
  int e = blockIdx.x * 256 + threadIdx.x;    // 8192 threads
  const float* p = edges + (size_t)e * NPF;
  float4 a, b;
  a.x = p[0]; a.y = p[1]; a.z = p[2]; a.w = p[NPF - 3];
  b.x = p[NPF - 2]; b.y = p[NPF - 1]; b.z = 0.f; b.w = 0.f;
  tbl4[(size_t)e * 2]     = a;
  tbl4[(size_t)e * 2 + 1] = b;
}

// ---- per-endpoint 16-NN edge lists, key = (d2bits<<32)|edge_idx ----
// Exactly the chain scan's ordering (same FMA dataflow, lexicographic key).
extern "C" __global__ void __launch_bounds__(256)
knn_kernel(const float4* __restrict__ tbl4, u64* __restrict__ lists)
{
  int q = blockIdx.x * 256 + threadIdx.x;    // 16384 threads (point id)
  float px, py, pz;
  {
    const float4* tp = tbl4 + (size_t)(q & (KE - 1)) * 2;
    float4 a = tp[0], b = tp[1];
    if (q < KE) { px = a.x; py = a.y; pz = a.z; }
    else        { px = a.w; py = b.x; pz = b.y; }
  }
  u64 kk[KNN];
#pragma unroll
  for (int i = 0; i < KNN; ++i) kk[i] = ~0ull;

  for (int e = 0; e < KE; ++e) {
    float4 a = tbl4[(size_t)e * 2];
    float4 b = tbl4[(size_t)e * 2 + 1];
    float d2s = dist2f(px, py, pz, a.x, a.y, a.z);
    float d2e = dist2f(px, py, pz, a.w, b.x, b.y);
    float v = fminf(d2s, d2e);
    u64 key = ((u64)__float_as_uint(v) << 32) | (unsigned)e;
    if (key < kk[KNN - 1]) {
      u64 c = key;
#pragma unroll
      for (int j = 0; j < KNN; ++j) {
        u64 lo = (kk[j] < c) ? kk[j] : c;
        c      = (kk[j] < c) ? c : kk[j];
        kk[j] = lo;
      }
    }
  }
  u64* lp = lists + (size_t)q * KNN;
#pragma unroll
  for (int i = 0; i < KNN; ++i) lp[i] = kk[i];
}

// One chain phase over steps [t0,t1). EPTT edges/thread live in registers.
template<int EPTT, bool FIRST>
__device__ void chain_phase(int t0, int t1,
    const float* __restrict__ edges, const float4* __restrict__ tbl4,
    float4* __restrict__ cmp, const u64* __restrict__ lists,
    unsigned* used_bm, int& Pio, int start_index,
    float& cxr, float& cyr, float& czr,
    unsigned* pk_lds, unsigned* d2_lds,
    u64 (*kbuf)[NW], int* s_int, int tid)
{
  constexpr int NPT = EPTT / 2;
  const int lane = tid & 63;
  const int wid  = tid >> 6;
  const int base = tid * EPTT;

  v2f sxp[NPT], syp[NPT], szp[NPT], exp_[NPT], eyp[NPT], ezp[NPT];
  int idxs[EPTT];   // unused when FIRST (optimized out)

#pragma unroll
  for (int e = 0; e < EPTT; ++e) {
    float a0, a1, a2, b0, b1, b2;
    if constexpr (FIRST) {
      const float* p = edges + (size_t)(base + e) * NPF;
      a0 = p[0]; a1 = p[1]; a2 = p[2];
      b0 = p[NPF - 3]; b1 = p[NPF - 2]; b2 = p[NPF - 1];
    } else {
      float4 a = cmp[(size_t)(base + e) * 2];
      float4 b = cmp[(size_t)(base + e) * 2 + 1];
      a0 = a.x; a1 = a.y; a2 = a.z; b0 = a.w; b1 = b.x; b2 = b.y;
      idxs[e] = __float_as_int(b.z);
    }
    if (e & 1) {
      sxp[e >> 1].y = a0; syp[e >> 1].y = a1; szp[e >> 1].y = a2;
      exp_[e >> 1].y = b0; eyp[e >> 1].y = b1; ezp[e >> 1].y = b2;
    } else {
      sxp[e >> 1].x = a0; syp[e >> 1].x = a1; szp[e >> 1].x = a2;
      exp_[e >> 1].x = b0; eyp[e >> 1].x = b1; ezp[e >> 1].x = b2;
    }
  }
  unsigned alive = (unsigned)((1u << EPTT) - 1);

  if constexpr (FIRST) {
    if (tid == (start_index / EPTT)) {
      int e = start_index & (EPTT - 1);
#pragma unroll
      for (int k = 0; k < NPT; ++k) {
        if ((e >> 1) == k) {
          if (e & 1) { sxp[k].y = INFINITY; exp_[k].y = INFINITY; }
          else       { sxp[k].x = INFINITY; exp_[k].x = INFINITY; }
        }
      }
      alive &= ~(1u << e);
    }
  }

  float cx = cxr, cy = cyr, cz = czr;
  int P = Pio;

  for (int t = t0; t < t1; ++t) {
    const int pb = t & 1;
    bool hit = false; int widx = 0; unsigned wd2 = 0;
    float pf0 = 0.f, pf1 = 0.f, pf2 = 0.f;   // candidate tbl prefetches

    if (lists) {
      __syncthreads();   // BARRIER_A: previous step's bitmap write visible
      const u64* lp = lists + (size_t)P * KNN;
      u64 kk[KNN];
#pragma unroll
      for (int i = 0; i < KNN; ++i) kk[i] = lp[i];
      // prefetch tbl lines of candidates 1..3 (kk[0] is own edge, used)
      if (tbl4) {
        pf0 = ((const float*)tbl4)[(size_t)(unsigned)(kk[1] & 0xFFFFFFFFu) * 8];
        pf1 = ((const float*)tbl4)[(size_t)(unsigned)(kk[2] & 0xFFFFFFFFu) * 8];
        pf2 = ((const float*)tbl4)[(size_t)(unsigned)(kk[3] & 0xFFFFFFFFu) * 8];
      }
      unsigned bw[KNN];
#pragma unroll
      for (int i = 0; i < KNN; ++i)
        bw[i] = used_bm[((unsigned)(kk[i] & 0xFFFFFFFFu)) >> 5];
#pragma unroll
      for (int i = 0; i < KNN; ++i) {
        int id = (int)(kk[i] & 0xFFFFFFFFu);
        if (!hit && !((bw[i] >> (id & 31)) & 1)) {
          hit = true; widx = id; wd2 = (unsigned)(kk[i] >> 32);
        }
      }
    }

    if (!hit) {
      // (A) packed FMA scan
      v2f cx2 = {cx, cx}, cy2 = {cy, cy}, cz2 = {cz, cz};
      float av0 = INFINITY, av1 = INFINITY, av2 = INFINITY, av3 = INFINITY;
      int   ai0 = 0x7FFFFFFF, ai1 = 0x7FFFFFFF, ai2 = 0x7FFFFFFF, ai3 = 0x7FFFFFFF;
#pragma unroll
      for (int p = 0; p < NPT; ++p) {
        v2f d2s = dist2p(cx2, cy2, cz2, sxp[p], syp[p], szp[p]);
        v2f d2e = dist2p(cx2, cy2, cz2, exp_[p], eyp[p], ezp[p]);
        v2f dm = __builtin_elementwise_min(d2s, d2e);
        int ix = FIRST ? (base + 2 * p)     : idxs[2 * p];
        int iy = FIRST ? (base + 2 * p + 1) : idxs[2 * p + 1];
        if ((p & 1) == 0) {
          if (dm.x < av0) { av0 = dm.x; ai0 = ix; }
          if (dm.y < av2) { av2 = dm.y; ai2 = iy; }
        } else {
          if (dm.x < av1) { av1 = dm.x; ai1 = ix; }
          if (dm.y < av3) { av3 = dm.y; ai3 = iy; }
        }
      }
      float mv = av0; int mi = ai0;
      if (av1 < mv || (av1 == mv && ai1 < mi)) { mv = av1; mi = ai1; }
      if (av2 < mv || (av2 == mv && ai2 < mi)) { mv = av2; mi = ai2; }
      if (av3 < mv || (av3 == mv && ai3 < mi)) { mv = av3; mi = ai3; }

      unsigned mvb = __float_as_uint(mv);
      unsigned x = mvb;
      DPPMIN(x, 0x111, 0xf);
      DPPMIN(x, 0x112, 0xf);
      DPPMIN(x, 0x114, 0xf);
      DPPMIN(x, 0x118, 0xf);
      DPPMIN(x, 0x142, 0xa);
      DPPMIN(x, 0x143, 0xc);
      unsigned wmin = (unsigned)__builtin_amdgcn_readlane((int)x, 63);
      u64 ball = __ballot(mvb == wmin);
      int win_lane = __ffsll(ball) - 1;
      if (lane == win_lane)
        kbuf[pb][wid] = ((u64)wmin << 32) | (unsigned)mi;
    }
    __syncthreads();   // BARRIER_B

    if (!hit) {
      const ulonglong2* kp = (const ulonglong2*)&kbuf[pb][0];
      ulonglong2 q0 = kp[0], q1 = kp[1], q2 = kp[2], q3 = kp[3];
      u64 kb = umin64(umin64(umin64(q0.x, q0.y), umin64(q1.x, q1.y)),
                      umin64(umin64(q2.x, q2.y), umin64(q3.x, q3.y)));
      widx = __builtin_amdgcn_readfirstlane((int)(kb & 0xFFFFFFFFu));
      wd2 = (unsigned)(kb >> 32);
    }

    float osx, osy, osz, oex, oey, oez;
    if (tbl4) {
      const float4* wp = tbl4 + (size_t)widx * 2;
      float4 a = wp[0], b = wp[1];
      osx = a.x; osy = a.y; osz = a.z; oex = a.w; oey = b.x; oez = b.y;
    } else {
      const float* wp = edges + (size_t)widx * NPF;
      osx = wp[0]; osy = wp[1]; osz = wp[2];
      oex = wp[NPF - 3]; oey = wp[NPF - 2]; oez = wp[NPF - 1];
    }

    // flip: numpy-exact (exact dist2 + exact sqrt compare)
    float da2 = dist2(cx, cy, cz, osx, osy, osz);
    float db2 = dist2(cx, cy, cz, oex, oey, oez);
    int fl = (sqrtf(da2) > sqrtf(db2)) ? 1 : 0;
    cx = fl ? osx : oex;
    cy = fl ? osy : oey;
    cz = fl ? osz : oez;
    P = fl ? widx : widx + KE;          // new endpoint's point id (uniform)

    // owner bookkeeping
    if constexpr (FIRST) {
      if (tid == (widx / EPTT)) {
        int e = widx & (EPTT - 1);
#pragma unroll
        for (int k = 0; k < NPT; ++k) {
          if ((e >> 1) == k) {
            if (e & 1) { sxp[k].y = INFINITY; exp_[k].y = INFINITY; }
            else       { sxp[k].x = INFINITY; exp_[k].x = INFINITY; }
          }
        }
        alive &= ~(1u << e);
        pk_lds[t + 1] = ((unsigned)widx << 1) | (unsigned)fl;
        d2_lds[t]     = wd2;
        if (lists) used_bm[widx >> 5] |= 1u << (widx & 31);
      }
    } else {
#pragma unroll
      for (int e = 0; e < EPTT; ++e) {
        if (idxs[e] == widx) {
          if (e & 1) { sxp[e >> 1].y = INFINITY; exp_[e >> 1].y = INFINITY; }
          else       { sxp[e >> 1].x = INFINITY; exp_[e >> 1].x = INFINITY; }
          alive &= ~(1u << e);
          pk_lds[t + 1] = ((unsigned)widx << 1) | (unsigned)fl;
          d2_lds[t]     = wd2;
          if (lists) used_bm[widx >> 5] |= 1u << (widx & 31);
        }
      }
    }
    // consume prefetch values AFTER the hot path (waitcnt lands here)
    asm volatile("" :: "v"(pf0), "v"(pf1), "v"(pf2));
  }

  cxr = cx; cyr = cy; czr = cz; Pio = P;

  // ---- compaction write-out (live edges, in ascending original index) ----
  if (t1 < KE - 1) {
    __syncthreads();                      // owner updates visible
    int cnt = __popc(alive);
    int sc = cnt;
#pragma unroll
    for (int m = 1; m < 64; m <<= 1) {
      int o = __shfl_up(sc, m);
      if (lane >= m) sc += o;
    }
    if (lane == 63) s_int[wid] = sc;
    __syncthreads();
    int wbase = 0;
#pragma unroll
    for (int w = 0; w < NW; ++w)
      if (w < wid) wbase += s_int[w];
    int pos = wbase + sc - cnt;
#pragma unroll
    for (int e = 0; e < EPTT; ++e) {
      if ((alive >> e) & 1) {
        float4 a, b;
        a.x = GETP(sxp, e); a.y = GETP(syp, e); a.z = GETP(szp, e);
        a.w = GETP(exp_, e);
        b.x = GETP(eyp, e); b.y = GETP(ezp, e);
        b.z = __int_as_float(FIRST ? (base + e) : idxs[e]); b.w = 0.f;
        cmp[(size_t)pos * 2]     = a;
        cmp[(size_t)pos * 2 + 1] = b;
        ++pos;
      }
    }
    __threadfence();
    __syncthreads();
  }
}

// Single-wave tail: live <= 1024, wave 0 only, NO barriers.
__device__ void chain_tail(int t0,
    const float4* __restrict__ cmp,
    float& cxr, float& cyr, float& czr,
    unsigned* pk_lds, unsigned* d2_lds,
    float4* s_ta, float4* s_tb, int lane)
{
  constexpr int E = 16, NPT = 8;
  const int base = lane * E;
  v2f sxp[NPT], syp[NPT], szp[NPT], exp_[NPT], eyp[NPT], ezp[NPT];

#pragma unroll
  for (int e = 0; e < E; ++e) {
    int pos = base + e;
    float4 a = cmp[(size_t)pos * 2];
    float4 b = cmp[(size_t)pos * 2 + 1];
    s_ta[pos] = a; s_tb[pos] = b;
    if (e & 1) {
      sxp[e >> 1].y = a.x; syp[e >> 1].y = a.y; szp[e >> 1].y = a.z;
      exp_[e >> 1].y = a.w; eyp[e >> 1].y = b.x; ezp[e >> 1].y = b.y;
    } else {
      sxp[e >> 1].x = a.x; syp[e >> 1].x = a.y; szp[e >> 1].x = a.z;
      exp_[e >> 1].x = a.w; eyp[e >> 1].x = b.x; ezp[e >> 1].x = b.y;
    }
  }

  float cx = cxr, cy = cyr, cz = czr;

  for (int t = t0; t < KE - 1; ++t) {
    v2f cx2 = {cx, cx}, cy2 = {cy, cy}, cz2 = {cz, cz};
    float av0 = INFINITY, av1 = INFINITY, av2 = INFINITY, av3 = INFINITY;
    int   ai0 = 0x7FFFFFFF, ai1 = 0x7FFFFFFF, ai2 = 0x7FFFFFFF, ai3 = 0x7FFFFFFF;
#pragma unroll
    for (int p = 0; p < NPT; ++p) {
      v2f d2s = dist2p(cx2, cy2, cz2, sxp[p], syp[p], szp[p]);
      v2f d2e = dist2p(cx2, cy2, cz2, exp_[p], eyp[p], ezp[p]);
      v2f dm = __builtin_elementwise_min(d2s, d2e);
      int ix = base + 2 * p;
      int iy = base + 2 * p + 1;
      if ((p & 1) == 0) {
        if (dm.x < av0) { av0 = dm.x; ai0 = ix; }
        if (dm.y < av2) { av2 = dm.y; ai2 = iy; }
      } else {
        if (dm.x < av1) { av1 = dm.x; ai1 = ix; }
        if (dm.y < av3) { av3 = dm.y; ai3 = iy; }
      }
    }
    float mv = av0; int mi = ai0;
    if (av1 < mv || (av1 == mv && ai1 < mi)) { mv = av1; mi = ai1; }
    if (av2 < mv || (av2 == mv && ai2 < mi)) { mv = av2; mi = ai2; }
    if (av3 < mv || (av3 == mv && ai3 < mi)) { mv = av3; mi = ai3; }

    unsigned mvb = __float_as_uint(mv);
    unsigned x = mvb;
    DPPMIN(x, 0x111, 0xf);
    DPPMIN(x, 0x112, 0xf);
    DPPMIN(x, 0x114, 0xf);
    DPPMIN(x, 0x118, 0xf);
    DPPMIN(x, 0x142, 0xa);
    DPPMIN(x, 0x143, 0xc);
    unsigned wmin = (unsigned)__builtin_amdgcn_readlane((int)x, 63);

    u64 ball = __ballot(mvb == wmin);
    int win_lane = __ffsll(ball) - 1;
    int wpos = __builtin_amdgcn_readlane(mi, win_lane);

    float4 a = s_ta[wpos];
    float4 b = s_tb[wpos];
    int orig = __float_as_int(b.z);

    float da2 = dist2(cx, cy, cz, a.x, a.y, a.z);
    float db2 = dist2(cx, cy, cz, a.w, b.x, b.y);
    int fl = (sqrtf(da2) > sqrtf(db2)) ? 1 : 0;
    cx = fl ? a.x : a.w;
    cy = fl ? a.y : b.x;
    cz = fl ? a.z : b.y;

    if (lane == win_lane) {
      int e = wpos & (E - 1);
#pragma unroll
      for (int k = 0; k < NPT; ++k) {
        if ((e >> 1) == k) {
          if (e & 1) { sxp[k].y = INFINITY; exp_[k].y = INFINITY; }
          else       { sxp[k].x = INFINITY; exp_[k].x = INFINITY; }
        }
      }
      pk_lds[t + 1] = ((unsigned)orig << 1) | (unsigned)fl;
      d2_lds[t]     = wmin;
    }
  }

  cxr = cx; cyr = cy; czr = cz;
}

extern "C" __global__ void __launch_bounds__(NT, 1)
chain_kernel(const float* __restrict__ edges, float* __restrict__ tail,
             int* __restrict__ ws_order, int* __restrict__ ws_flip,
             float* __restrict__ tbl, float4* __restrict__ cmp,
             const u64* __restrict__ lists)
{
  const int tid = threadIdx.x;
  const int lane = tid & 63;
  const int wid = tid >> 6;          // 0..7
  const int base = tid * EPT;

  __shared__ __align__(16) u64 kbuf[2][NW];
  __shared__ float  s_v[NW];
  __shared__ int    s_i[NW];
  __shared__ float  s_m1[NW], s_m2[NW];
  __shared__ unsigned pk_lds[KE];
  __shared__ unsigned d2_lds[KE];
  __shared__ unsigned used_bm[KE / 32];         // 1KB used bitmap
  __shared__ __align__(16) float4 s_ta[1024];   // tail coord table
  __shared__ __align__(16) float4 s_tb[1024];

  if (tid < KE / 32) used_bm[tid] = 0u;

  // ---- init: load endpoints ----
  v2f sxp[EPT / 2], syp[EPT / 2], szp[EPT / 2];
  v2f exp_[EPT / 2], eyp[EPT / 2], ezp[EPT / 2];
#pragma unroll
  for (int e = 0; e < EPT; ++e) {
    const float* p = edges + (size_t)(base + e) * NPF;
    float a0 = p[0], a1 = p[1], a2 = p[2];
    float b0 = p[NPF - 3], b1 = p[NPF - 2], b2 = p[NPF - 1];
    if (e & 1) {
      sxp[e >> 1].y = a0; syp[e >> 1].y = a1; szp[e >> 1].y = a2;
      exp_[e >> 1].y = b0; eyp[e >> 1].y = b1; ezp[e >> 1].y = b2;
    } else {
      sxp[e >> 1].x = a0; syp[e >> 1].x = a1; szp[e >> 1].x = a2;
      exp_[e >> 1].x = b0; eyp[e >> 1].x = b1; ezp[e >> 1].x = b2;
    }
  }

  // ---- write compact endpoint table (idempotent vs tbl_build) ----
  if (tbl) {
#pragma unroll
    for (int e = 0; e < EPT; ++e) {
      float4 a, b;
      a.x = GETP(sxp, e); a.y = GETP(syp, e); a.z = GETP(szp, e); a.w = GETP(exp_, e);
      b.x = GETP(eyp, e); b.y = GETP(ezp, e); b.z = 0.f; b.w = 0.f;
      ((float4*)tbl)[(size_t)(base + e) * 2]     = a;
      ((float4*)tbl)[(size_t)(base + e) * 2 + 1] = b;
    }
  }

  // ---- lengths; top-10; start_index = max index among them ----
  float len[EPT];
#pragma unroll
  for (int e = 0; e < EPT; ++e)
    len[e] = dist3(GETP(exp_, e), GETP(eyp, e), GETP(ezp, e),
                   GETP(sxp, e), GETP(syp, e), GETP(szp, e));

  unsigned tk = 0;
  int start_index = -1;
  for (int r = 0; r < TOPK_N; ++r) {
    float bv = -INFINITY; int bi = 0x7fffffff;
#pragma unroll
    for (int e = 0; e < EPT; ++e) {
      if ((tk >> e) & 1) continue;
      if (len[e] > bv) { bv = len[e]; bi = base + e; }
    }
    for (int m = 1; m < 64; m <<= 1) {
      float v2 = __shfl_xor(bv, m); int i2 = __shfl_xor(bi, m);
      if (v2 > bv || (v2 == bv && i2 < bi)) { bv = v2; bi = i2; }
    }
    if (lane == 0) { s_v[wid] = bv; s_i[wid] = bi; }
    __syncthreads();
    {
      float cv = s_v[lane & (NW - 1)]; int ci = s_i[lane & (NW - 1)];
      for (int m = 1; m < NW; m <<= 1) {
        float v2 = __shfl_xor(cv, m); int i2 = __shfl_xor(ci, m);
        if (v2 > cv || (v2 == cv && i2 < ci)) { cv = v2; ci = i2; }
      }
      int sel = ci;
      if ((sel / EPT) == tid) tk |= 1u << (sel & (EPT - 1));
      if (sel > start_index) start_index = sel;
    }
    __syncthreads();
  }

  // ---- s0 / e0: uniform global load ----
  float s0x, s0y, s0z, e0x, e0y, e0z;
  {
    const float* p = edges + (size_t)start_index * NPF;
    s0x = p[0];       s0y = p[1];       s0z = p[2];
    e0x = p[NPF - 3]; e0y = p[NPF - 2]; e0z = p[NPF - 1];
  }

  // ---- use_flip0 (numpy-exact; sqrt(min)==min(sqrt)) ----
  {
    float m1 = INFINITY, m2 = INFINITY;
#pragma unroll
    for (int e = 0; e < EPT; ++e) {
      int k = base + e;
      float a = dist2(s0x, s0y, s0z, GETP(sxp, e), GETP(syp, e), GETP(szp, e));
      float b = dist2(s0x, s0y, s0z, GETP(exp_, e), GETP(eyp, e), GETP(ezp, e));
      float c = dist2(e0x, e0y, e0z, GETP(sxp, e), GETP(syp, e), GETP(szp, e));
      float d = dist2(e0x, e0y, e0z, GETP(exp_, e), GETP(eyp, e), GETP(ezp, e));
      float v1 = fminf(a, b), v2 = fminf(c, d);
      if (k == start_index) { v1 = INFINITY; v2 = INFINITY; }
      m1 = fminf(m1, v1);
      m2 = fminf(m2, v2);
    }
    for (int m = 1; m < 64; m <<= 1) {
      m1 = fminf(m1, __shfl_xor(m1, m));
      m2 = fminf(m2, __shfl_xor(m2, m));
    }
    if (lane == 0) { s_m1[wid] = m1; s_m2[wid] = m2; }
  }
  __syncthreads();

  float cx, cy, cz, fx, fy, fz;
  int flip0;
  {
    float m1 = s_m1[lane & (NW - 1)], m2 = s_m2[lane & (NW - 1)];
    for (int m = 1; m < NW; m <<= 1) {
      m1 = fminf(m1, __shfl_xor(m1, m));
      m2 = fminf(m2, __shfl_xor(m2, m));
    }
    flip0 = (sqrtf(m1) < sqrtf(m2)) ? 1 : 0;
    cx = flip0 ? s0x : e0x;  cy = flip0 ? s0y : e0y;  cz = flip0 ? s0z : e0z;
    fx = flip0 ? e0x : s0x;  fy = flip0 ? e0y : s0y;  fz = flip0 ? e0z : s0z;
    if (tid == 0) {
      pk_lds[0] = ((unsigned)start_index << 1) | (unsigned)flip0;
      used_bm[start_index >> 5] = 1u << (start_index & 31);
    }
  }
  __syncthreads();

  int P = flip0 ? start_index : start_index + KE;   // cur's point id

  // ---- phased greedy chain ----
  if (cmp) {
    chain_phase<16, true >(0,    4095, edges, (const float4*)tbl, cmp, lists,
                           used_bm, P, start_index, cx, cy, cz,
                           pk_lds, d2_lds, kbuf, s_i, tid);
    chain_phase<8, false>(4095, 6143, edges, (const float4*)tbl, cmp, lists,
                           used_bm, P, start_index, cx, cy, cz,
                           pk_lds, d2_lds, kbuf, s_i, tid);
    chain_phase<4, false>(6143, 7167, edges, (const float4*)tbl, cmp, lists,
                           used_bm, P, start_index, cx, cy, cz,
                           pk_lds, d2_lds, kbuf, s_i, tid);
    if (wid == 0)
      chain_tail(7167, cmp, cx, cy, cz, pk_lds, d2_lds, s_ta, s_tb, lane);
  } else {
    chain_phase<16, true >(0, KE - 1, edges, (const float4*)tbl, cmp, nullptr,
                           used_bm, P, start_index, cx, cy, cz,
                           pk_lds, d2_lds, kbuf, s_i, tid);
  }

  // closing squared distance -> d2_lds[KE-1] (sqrt at flush)
  if (tid == 0)
    d2_lds[KE - 1] = __float_as_uint(dist2(cx, cy, cz, fx, fy, fz));
  __syncthreads();

  // ---- final flush: LDS -> global (order | flips | distances | ws) ----
  float* ord_f = tail;
  float* flp_f = tail + KE;
  float* dst_f = tail + 2 * KE;
#pragma unroll
  for (int k = 0; k < EPT; ++k) {
    int i = tid + k * NT;
    unsigned p = pk_lds[i];
    int w = (int)(p >> 1);
    int f = (int)(p & 1u);
    ord_f[i] = (float)w;
    flp_f[i] = (float)f;
    dst_f[i] = sqrtf(__uint_as_float(d2_lds[i]));
    ws_order[i] = w;
    ws_flip[i]  = f;
  }
}

extern "C" __global__ void __launch_bounds__(256)
gather_kernel(const float* __restrict__ edges, const int* __restrict__ ws_order,
              const int* __restrict__ ws_flip, float* __restrict__ out)
{
  int idx = blockIdx.x * 256 + threadIdx.x;   // < 25165824, fits int
  int i = idx / NPF;
  int f = idx - i * NPF;
  int o  = ws_order[i];
  int fl = ws_flip[i];
  int r = f / 3;
  int c = f - r * 3;
  int srcf = fl ? ((1023 - r) * 3 + c) : f;
  out[idx] = edges[o * NPF + srcf];
}

extern "C" void kernel_launch(void* const* d_in, const int* in_sizes, int n_in,
                              void* d_out, int out_size, void* d_ws, size_t ws_size,
                              hipStream_t stream) {
  (void)in_sizes; (void)n_in; (void)out_size;
  const float* edges = (const float*)d_in[0];
  float* out  = (float*)d_out;
  float* tail = out + (size_t)KE * NPF;        // order | flips | distances
  int* ws_order = (int*)d_ws;
  int* ws_flip  = ws_order + KE;

  size_t off_tbl = (size_t)2 * KE * sizeof(int);              //  64 KB
  size_t off_cmp = off_tbl + (size_t)KE * 8 * sizeof(float);  // +256 KB
  size_t off_lst = off_cmp + (size_t)4096 * 8 * sizeof(float);// +128 KB
  size_t need_lst = off_lst + (size_t)2 * KE * KNN * sizeof(u64); // +2 MB

  float*  tbl   = (ws_size >= off_cmp) ? (float*)((char*)d_ws + off_tbl) : nullptr;
  float4* cmp   = (ws_size >= off_lst && tbl) ? (float4*)((char*)d_ws + off_cmp) : nullptr;
  u64*    lists = (ws_size >= need_lst && cmp) ? (u64*)((char*)d_ws + off_lst) : nullptr;

  if (lists) {
    hipLaunchKernelGGL(tbl_build_kernel, dim3(KE / 256), dim3(256), 0, stream,
                       edges, (float4*)tbl);
    hipLaunchKernelGGL(knn_kernel, dim3(2 * KE / 256), dim3(256), 0, stream,
                       (const float4*)tbl, lists);
  }
  hipLaunchKernelGGL(chain_kernel, dim3(1), dim3(NT), 0, stream,
                     edges, tail, ws_order, ws_flip, tbl, cmp,
                     (const u64*)lists);
  hipLaunchKernelGGL(gather_kernel, dim3((KE * NPF) / 256), dim3(256), 0, stream,
                     edges, ws_order, ws_flip, out);
}

// Round 17
// 14228.548 us; speedup vs baseline: 1.1562x; 1.1562x over previous
//
#include <hip/hip_runtime.h>
#include <math.h>
#include <float.h>

#define KE 8192        // number of edges
#define NPF 3072       // floats per edge (1024 * 3)
#define NT 512         // threads (wave 0 runs the chain; waves 1-7 warm L2)
#define EPT 16         // edges per thread in init phase
#define NW  8          // waves
#define TOPK_N 10
#define KNN 16         // candidate list length
#define TAIL_T 7167    // main loop steps; live at tail start = 1024

typedef unsigned long long u64;
typedef float v2f __attribute__((ext_vector_type(2)));

#define GETP(arr, k) (((k) & 1) ? arr[(k) >> 1].y : arr[(k) >> 1].x)

#define DPPMIN(x, ctrl, rmask)                                              \
  do {                                                                      \
    unsigned _t = (unsigned)__builtin_amdgcn_update_dpp(                    \
        (int)0xFFFFFFFF, (int)(x), (ctrl), (rmask), 0xf, false);            \
    (x) = ((x) < _t) ? (x) : _t;                                            \
  } while (0)

// numpy-exact squared distance (no contraction) for DISCRETE decisions
__device__ __forceinline__ float dist2(float ax, float ay, float az,
                                       float bx, float by, float bz) {
#pragma clang fp contract(off)
  float dx = ax - bx, dy = ay - by, dz = az - bz;
  float s = (dx * dx + dy * dy) + dz * dz;
  return s;
}

// packed 2-edge squared distance, FMA form (argmin-safe; certified by bench)
__device__ __forceinline__ v2f dist2p(v2f cx, v2f cy, v2f cz,
                                      v2f px, v2f py, v2f pz) {
  v2f dx = px - cx, dy = py - cy, dz = pz - cz;
  return __builtin_elementwise_fma(dx, dx,
           __builtin_elementwise_fma(dy, dy, dz * dz));
}

// scalar twin of dist2p: IDENTICAL dataflow -> bitwise-identical values
__device__ __forceinline__ float dist2f(float cx, float cy, float cz,
                                        float px, float py, float pz) {
  float dx = px - cx, dy = py - cy, dz = pz - cz;
  return fmaf(dx, dx, fmaf(dy, dy, dz * dz));
}

__device__ __forceinline__ float dist3(float ax, float ay, float az,
                                       float bx, float by, float bz) {
  return sqrtf(dist2(ax, ay, az, bx, by, bz));
}

// ---- build the compact 32B/edge endpoint table ----
extern "C" __global__ void __launch_bounds__(256)
tbl_build_kernel(const float* __restrict__ edges, float4* __restrict__ tbl4)
{
  int e = blockIdx.x * 256 + threadIdx.x;    // 8192 threads
  const float* p = edges + (size_t)e * NPF;
  float4 a, b;
  a.x = p[0]; a.y = p[1]; a.z = p[2]; a.w = p[NPF - 3];
  b.x = p[NPF - 2]; b.y = p[NPF - 1]; b.z = 0.f; b.w = 0.f;
  tbl4[(size_t)e * 2]     = a;
  tbl4[(size_t)e * 2 + 1] = b;
}

// ---- per-endpoint 16-NN edge lists, key = (d2bits<<32)|edge_idx ----
extern "C" __global__ void __launch_bounds__(64)
knn_kernel(const float4* __restrict__ tbl4, u64* __restrict__ lists)
{
  int q = blockIdx.x * 64 + threadIdx.x;     // 16384 threads (point id)
  float px, py, pz;
  {
    const float4* tp = tbl4 + (size_t)(q & (KE - 1)) * 2;
    float4 a = tp[0], b = tp[1];
    if (q < KE) { px = a.x; py = a.y; pz = a.z; }
    else        { px = a.w; py = b.x; pz = b.y; }
  }
  u64 kk[KNN];
#pragma unroll
  for (int i = 0; i < KNN; ++i) kk[i] = ~0ull;

  for (int e = 0; e < KE; ++e) {
    float4 a = tbl4[(size_t)e * 2];
    float4 b = tbl4[(size_t)e * 2 + 1];
    float d2s = dist2f(px, py, pz, a.x, a.y, a.z);
    float d2e = dist2f(px, py, pz, a.w, b.x, b.y);
    float v = fminf(d2s, d2e);
    u64 key = ((u64)__float_as_uint(v) << 32) | (unsigned)e;
    if (key < kk[KNN - 1]) {
      u64 c = key;
#pragma unroll
      for (int j = 0; j < KNN; ++j) {
        u64 lo = (kk[j] < c) ? kk[j] : c;
        c      = (kk[j] < c) ? c : kk[j];
        kk[j] = lo;
      }
    }
  }
  u64* lp = lists + (size_t)q * KNN;
#pragma unroll
  for (int i = 0; i < KNN; ++i) lp[i] = kk[i];
}

// single-wave masked full scan (miss fallback). Lane-major edge layout:
// lane l owns edges [l*128,(l+1)*128) -> lane order == index order.
__device__ void sw_scan(const float4* __restrict__ tbl4,
                        const float* __restrict__ edges,
                        unsigned m0, unsigned m1, unsigned m2, unsigned m3,
                        float cx, float cy, float cz, int lane,
                        int& widx_o, unsigned& wd2_o)
{
  float av0 = INFINITY, av1 = INFINITY, av2 = INFINITY, av3 = INFINITY;
  int   ai0 = 0, ai1 = 0, ai2 = 0, ai3 = 0;
#pragma unroll
  for (int w = 0; w < 4; ++w) {
    unsigned mw = (w == 0) ? m0 : (w == 1) ? m1 : (w == 2) ? m2 : m3;
    for (int k8 = 0; k8 < 8; ++k8) {
#pragma unroll
      for (int j = 0; j < 4; ++j) {
        int k = w * 32 + k8 * 4 + j;
        int e = (lane << 7) + k;
        float sx, sy, sz, ex, ey, ez;
        if (tbl4) {
          float4 a = tbl4[(size_t)e * 2], b = tbl4[(size_t)e * 2 + 1];
          sx = a.x; sy = a.y; sz = a.z; ex = a.w; ey = b.x; ez = b.y;
        } else {
          const float* p = edges + (size_t)e * NPF;
          sx = p[0]; sy = p[1]; sz = p[2];
          ex = p[NPF - 3]; ey = p[NPF - 2]; ez = p[NPF - 1];
        }
        float v = fminf(dist2f(cx, cy, cz, sx, sy, sz),
                        dist2f(cx, cy, cz, ex, ey, ez));
        v = ((mw >> (k & 31)) & 1) ? v : INFINITY;
        if (j == 0)      { if (v < av0) { av0 = v; ai0 = e; } }
        else if (j == 1) { if (v < av1) { av1 = v; ai1 = e; } }
        else if (j == 2) { if (v < av2) { av2 = v; ai2 = e; } }
        else             { if (v < av3) { av3 = v; ai3 = e; } }
      }
    }
  }
  float mv = av0; int mi = ai0;
  if (av1 < mv || (av1 == mv && ai1 < mi)) { mv = av1; mi = ai1; }
  if (av2 < mv || (av2 == mv && ai2 < mi)) { mv = av2; mi = ai2; }
  if (av3 < mv || (av3 == mv && ai3 < mi)) { mv = av3; mi = ai3; }

  unsigned mvb = __float_as_uint(mv);
  unsigned x = mvb;
  DPPMIN(x, 0x111, 0xf);
  DPPMIN(x, 0x112, 0xf);
  DPPMIN(x, 0x114, 0xf);
  DPPMIN(x, 0x118, 0xf);
  DPPMIN(x, 0x142, 0xa);
  DPPMIN(x, 0x143, 0xc);
  unsigned wmin = (unsigned)__builtin_amdgcn_readlane((int)x, 63);
  u64 ball = __ballot(mvb == wmin);
  int first = __ffsll(ball) - 1;          // lowest lane = lowest index
  widx_o = __builtin_amdgcn_readlane(mi, first);
  wd2_o  = wmin;
}

// R15-proven single-wave tail over the compacted 1024-entry LDS table.
__device__ void chain_tail(float& cxr, float& cyr, float& czr,
    unsigned* pk_lds, unsigned* d2_lds,
    const float4* s_ta, const float4* s_tb, int lane)
{
  constexpr int E = 16, NPT = 8;
  const int base = lane * E;
  v2f sxp[NPT], syp[NPT], szp[NPT], exp_[NPT], eyp[NPT], ezp[NPT];

#pragma unroll
  for (int e = 0; e < E; ++e) {
    float4 a = s_ta[base + e];
    float4 b = s_tb[base + e];
    if (e & 1) {
      sxp[e >> 1].y = a.x; syp[e >> 1].y = a.y; szp[e >> 1].y = a.z;
      exp_[e >> 1].y = a.w; eyp[e >> 1].y = b.x; ezp[e >> 1].y = b.y;
    } else {
      sxp[e >> 1].x = a.x; syp[e >> 1].x = a.y; szp[e >> 1].x = a.z;
      exp_[e >> 1].x = a.w; eyp[e >> 1].x = b.x; ezp[e >> 1].x = b.y;
    }
  }

  float cx = cxr, cy = cyr, cz = czr;

  for (int t = TAIL_T; t < KE - 1; ++t) {
    v2f cx2 = {cx, cx}, cy2 = {cy, cy}, cz2 = {cz, cz};
    float av0 = INFINITY, av1 = INFINITY, av2 = INFINITY, av3 = INFINITY;
    int   ai0 = 0, ai1 = 0, ai2 = 0, ai3 = 0;
#pragma unroll
    for (int p = 0; p < NPT; ++p) {
      v2f d2s = dist2p(cx2, cy2, cz2, sxp[p], syp[p], szp[p]);
      v2f d2e = dist2p(cx2, cy2, cz2, exp_[p], eyp[p], ezp[p]);
      v2f dm = __builtin_elementwise_min(d2s, d2e);
      int ix = base + 2 * p;
      int iy = base + 2 * p + 1;
      if ((p & 1) == 0) {
        if (dm.x < av0) { av0 = dm.x; ai0 = ix; }
        if (dm.y < av2) { av2 = dm.y; ai2 = iy; }
      } else {
        if (dm.x < av1) { av1 = dm.x; ai1 = ix; }
        if (dm.y < av3) { av3 = dm.y; ai3 = iy; }
      }
    }
    float mv = av0; int mi = ai0;
    if (av1 < mv || (av1 == mv && ai1 < mi)) { mv = av1; mi = ai1; }
    if (av2 < mv || (av2 == mv && ai2 < mi)) { mv = av2; mi = ai2; }
    if (av3 < mv || (av3 == mv && ai3 < mi)) { mv = av3; mi = ai3; }

    unsigned mvb = __float_as_uint(mv);
    unsigned x = mvb;
    DPPMIN(x, 0x111, 0xf);
    DPPMIN(x, 0x112, 0xf);
    DPPMIN(x, 0x114, 0xf);
    DPPMIN(x, 0x118, 0xf);
    DPPMIN(x, 0x142, 0xa);
    DPPMIN(x, 0x143, 0xc);
    unsigned wmin = (unsigned)__builtin_amdgcn_readlane((int)x, 63);

    u64 ball = __ballot(mvb == wmin);
    int win_lane = __ffsll(ball) - 1;
    int wpos = __builtin_amdgcn_readlane(mi, win_lane);

    float4 a = s_ta[wpos];
    float4 b = s_tb[wpos];
    int orig = __float_as_int(b.z);

    float da2 = dist2(cx, cy, cz, a.x, a.y, a.z);
    float db2 = dist2(cx, cy, cz, a.w, b.x, b.y);
    int fl = (sqrtf(da2) > sqrtf(db2)) ? 1 : 0;
    cx = fl ? a.x : a.w;
    cy = fl ? a.y : b.x;
    cz = fl ? a.z : b.y;

    if (lane == win_lane) {
      int e = wpos & (E - 1);
#pragma unroll
      for (int k = 0; k < NPT; ++k) {
        if ((e >> 1) == k) {
          if (e & 1) { sxp[k].y = INFINITY; exp_[k].y = INFINITY; }
          else       { sxp[k].x = INFINITY; exp_[k].x = INFINITY; }
        }
      }
      pk_lds[t + 1] = ((unsigned)orig << 1) | (unsigned)fl;
      d2_lds[t]     = wmin;
    }
  }

  cxr = cx; cyr = cy; czr = cz;
}

extern "C" __global__ void __launch_bounds__(NT, 1)
chain_kernel(const float* __restrict__ edges, float* __restrict__ tail,
             int* __restrict__ ws_order, int* __restrict__ ws_flip,
             float* __restrict__ tbl, const u64* __restrict__ lists)
{
  const int tid = threadIdx.x;
  const int lane = tid & 63;
  const int wid = tid >> 6;          // 0..7
  const int base = tid * EPT;
  const float4* tbl4 = (const float4*)tbl;

  __shared__ float  s_v[NW];
  __shared__ int    s_i[NW];
  __shared__ float  s_m1[NW], s_m2[NW];
  __shared__ unsigned pk_lds[KE];
  __shared__ unsigned d2_lds[KE];
  __shared__ unsigned used_bm[KE / 32];         // 1KB used bitmap
  __shared__ __align__(16) float4 s_ta[1024];   // tail coord table
  __shared__ __align__(16) float4 s_tb[1024];

  if (tid < KE / 32) used_bm[tid] = 0u;

  // ---- init: load endpoints into registers (512 threads) ----
  v2f sxp[EPT / 2], syp[EPT / 2], szp[EPT / 2];
  v2f exp_[EPT / 2], eyp[EPT / 2], ezp[EPT / 2];
#pragma unroll
  for (int e = 0; e < EPT; ++e) {
    const float* p = edges + (size_t)(base + e) * NPF;
    float a0 = p[0], a1 = p[1], a2 = p[2];
    float b0 = p[NPF - 3], b1 = p[NPF - 2], b2 = p[NPF - 1];
    if (e & 1) {
      sxp[e >> 1].y = a0; syp[e >> 1].y = a1; szp[e >> 1].y = a2;
      exp_[e >> 1].y = b0; eyp[e >> 1].y = b1; ezp[e >> 1].y = b2;
    } else {
      sxp[e >> 1].x = a0; syp[e >> 1].x = a1; szp[e >> 1].x = a2;
      exp_[e >> 1].x = b0; eyp[e >> 1].x = b1; ezp[e >> 1].x = b2;
    }
  }

  // ---- lengths; top-10; start_index = max index among them ----
  float len[EPT];
#pragma unroll
  for (int e = 0; e < EPT; ++e)
    len[e] = dist3(GETP(exp_, e), GETP(eyp, e), GETP(ezp, e),
                   GETP(sxp, e), GETP(syp, e), GETP(szp, e));

  unsigned tk = 0;
  int start_index = -1;
  for (int r = 0; r < TOPK_N; ++r) {
    float bv = -INFINITY; int bi = 0x7fffffff;
#pragma unroll
    for (int e = 0; e < EPT; ++e) {
      if ((tk >> e) & 1) continue;
      if (len[e] > bv) { bv = len[e]; bi = base + e; }
    }
    for (int m = 1; m < 64; m <<= 1) {
      float v2 = __shfl_xor(bv, m); int i2 = __shfl_xor(bi, m);
      if (v2 > bv || (v2 == bv && i2 < bi)) { bv = v2; bi = i2; }
    }
    if (lane == 0) { s_v[wid] = bv; s_i[wid] = bi; }
    __syncthreads();
    {
      float cv = s_v[lane & (NW - 1)]; int ci = s_i[lane & (NW - 1)];
      for (int m = 1; m < NW; m <<= 1) {
        float v2 = __shfl_xor(cv, m); int i2 = __shfl_xor(ci, m);
        if (v2 > cv || (v2 == cv && i2 < ci)) { cv = v2; ci = i2; }
      }
      int sel = ci;
      if ((sel / EPT) == tid) tk |= 1u << (sel & (EPT - 1));
      if (sel > start_index) start_index = sel;
    }
    __syncthreads();
  }

  // ---- s0 / e0: uniform global load ----
  float s0x, s0y, s0z, e0x, e0y, e0z;
  {
    const float* p = edges + (size_t)start_index * NPF;
    s0x = p[0];       s0y = p[1];       s0z = p[2];
    e0x = p[NPF - 3]; e0y = p[NPF - 2]; e0z = p[NPF - 1];
  }

  // ---- use_flip0 (numpy-exact; sqrt(min)==min(sqrt)) ----
  {
    float m1 = INFINITY, m2 = INFINITY;
#pragma unroll
    for (int e = 0; e < EPT; ++e) {
      int k = base + e;
      float a = dist2(s0x, s0y, s0z, GETP(sxp, e), GETP(syp, e), GETP(szp, e));
      float b = dist2(s0x, s0y, s0z, GETP(exp_, e), GETP(eyp, e), GETP(ezp, e));
      float c = dist2(e0x, e0y, e0z, GETP(sxp, e), GETP(syp, e), GETP(szp, e));
      float d = dist2(e0x, e0y, e0z, GETP(exp_, e), GETP(eyp, e), GETP(ezp, e));
      float v1 = fminf(a, b), v2 = fminf(c, d);
      if (k == start_index) { v1 = INFINITY; v2 = INFINITY; }
      m1 = fminf(m1, v1);
      m2 = fminf(m2, v2);
    }
    for (int m = 1; m < 64; m <<= 1) {
      m1 = fminf(m1, __shfl_xor(m1, m));
      m2 = fminf(m2, __shfl_xor(m2, m));
    }
    if (lane == 0) { s_m1[wid] = m1; s_m2[wid] = m2; }
  }
  __syncthreads();

  float cx, cy, cz, fx, fy, fz;
  int flip0;
  {
    float m1 = s_m1[lane & (NW - 1)], m2 = s_m2[lane & (NW - 1)];
    for (int m = 1; m < NW; m <<= 1) {
      m1 = fminf(m1, __shfl_xor(m1, m));
      m2 = fminf(m2, __shfl_xor(m2, m));
    }
    flip0 = (sqrtf(m1) < sqrtf(m2)) ? 1 : 0;
    cx = flip0 ? s0x : e0x;  cy = flip0 ? s0y : e0y;  cz = flip0 ? s0z : e0z;
    fx = flip0 ? e0x : s0x;  fy = flip0 ? e0y : s0y;  fz = flip0 ? e0z : s0z;
    if (tid == 0) {
      pk_lds[0] = ((unsigned)start_index << 1) | (unsigned)flip0;
      used_bm[start_index >> 5] = 1u << (start_index & 31);
    }
  }
  __syncthreads();

  if (wid == 0) {
    // ================= single-wave chain, ZERO barriers =================
    // per-lane alive masks: lane l owns edges [l*128,(l+1)*128)
    unsigned m0 = ~0u, m1 = ~0u, m2 = ~0u, m3 = ~0u;
    if (lane == (start_index >> 7)) {
      int k = start_index & 127;
      unsigned bit = 1u << (k & 31);
      int wsel = k >> 5;
      if (wsel == 0) m0 &= ~bit;
      else if (wsel == 1) m1 &= ~bit;
      else if (wsel == 2) m2 &= ~bit;
      else m3 &= ~bit;
    }

    // bootstrap prefetch: windows for widx = start_index
    u64 pf = 0;
    int win = (lane >> 4) & 3;
    if (lists) {
      if (win == 1) pf = lists[(size_t)start_index * KNN + (lane & 15)];
      else if (win == 2) pf = lists[(size_t)(start_index + KE) * KNN + (lane & 15)];
    }
    int fl_prev = flip0;

    for (int t = 0; t < TAIL_T; ++t) {
      int widx; unsigned wd2;
      bool hit = false;
      if (lists) {
        // 1. select current candidate list (lane i -> candidate i)
        int src = (fl_prev ? 16 : 32) + (lane & 15);
        u64 kk = __shfl(pf, src);
        unsigned klo = (unsigned)kk, khi = (unsigned)(kk >> 32);
        // 2. bitmap check + first unused (global argmin when hit)
        unsigned w = used_bm[klo >> 5];
        bool unused = (lane < 16) && !((w >> (klo & 31)) & 1);
        u64 ball = __ballot(unused);
        if (ball) {
          hit = true;
          int first = __ffsll(ball) - 1;
          widx = __builtin_amdgcn_readlane((int)klo, first);
          wd2  = (unsigned)__builtin_amdgcn_readlane((int)khi, first);
        }
      }
      if (!hit)
        sw_scan(tbl4, edges, m0, m1, m2, m3, cx, cy, cz, lane, widx, wd2);

      // 3. prefetch next-step lists EARLY (both flip options of winner)
      if (lists) {
        if (win == 1) pf = lists[(size_t)widx * KNN + (lane & 15)];
        else if (win == 2) pf = lists[(size_t)(widx + KE) * KNN + (lane & 15)];
      }

      // 4. winner coords (uniform, L2-warm) + exact flip
      float osx, osy, osz, oex, oey, oez;
      if (tbl4) {
        float4 a = tbl4[(size_t)widx * 2], b = tbl4[(size_t)widx * 2 + 1];
        osx = a.x; osy = a.y; osz = a.z; oex = a.w; oey = b.x; oez = b.y;
      } else {
        const float* wp = edges + (size_t)widx * NPF;
        osx = wp[0]; osy = wp[1]; osz = wp[2];
        oex = wp[NPF - 3]; oey = wp[NPF - 2]; oez = wp[NPF - 1];
      }
      float da2 = dist2(cx, cy, cz, osx, osy, osz);
      float db2 = dist2(cx, cy, cz, oex, oey, oez);
      int fl = (sqrtf(da2) > sqrtf(db2)) ? 1 : 0;
      cx = fl ? osx : oex;
      cy = fl ? osy : oey;
      cz = fl ? osz : oez;

      // 5. bookkeeping (LDS bitmap by lane 0; register mask by owner lane)
      if (lane == 0) {
        used_bm[widx >> 5] |= 1u << (widx & 31);
        pk_lds[t + 1] = ((unsigned)widx << 1) | (unsigned)fl;
        d2_lds[t] = wd2;
      }
      if (lane == (widx >> 7)) {
        int k = widx & 127;
        unsigned bit = 1u << (k & 31);
        int wsel = k >> 5;
        if (wsel == 0) m0 &= ~bit;
        else if (wsel == 1) m1 &= ~bit;
        else if (wsel == 2) m2 &= ~bit;
        else m3 &= ~bit;
      }
      fl_prev = fl;
    }

    // ---- build compacted LDS table (1024 live, ascending index) ----
    {
      int cnt = __popc(m0) + __popc(m1) + __popc(m2) + __popc(m3);
      int sc = cnt;
#pragma unroll
      for (int sh = 1; sh < 64; sh <<= 1) {
        int o = __shfl_up(sc, sh);
        if (lane >= sh) sc += o;
      }
      int pos = sc - cnt;
#pragma unroll
      for (int w = 0; w < 4; ++w) {
        unsigned mw = (w == 0) ? m0 : (w == 1) ? m1 : (w == 2) ? m2 : m3;
        while (mw) {
          int b = __ffs(mw) - 1; mw &= mw - 1;
          int e = (lane << 7) + (w << 5) + b;
          float4 a, bb;
          if (tbl4) {
            a = tbl4[(size_t)e * 2]; bb = tbl4[(size_t)e * 2 + 1];
          } else {
            const float* p = edges + (size_t)e * NPF;
            a.x = p[0]; a.y = p[1]; a.z = p[2]; a.w = p[NPF - 3];
            bb.x = p[NPF - 2]; bb.y = p[NPF - 1]; bb.z = 0.f; bb.w = 0.f;
          }
          bb.z = __int_as_float(e);
          s_ta[pos] = a; s_tb[pos] = bb; ++pos;
        }
      }
    }

    // ---- tail: compacted single-wave scan (proven R15 structure) ----
    chain_tail(cx, cy, cz, pk_lds, d2_lds, s_ta, s_tb, lane);

    if (lane == 0)
      d2_lds[KE - 1] = __float_as_uint(dist2(cx, cy, cz, fx, fy, fz));
  } else if (lists) {
    // ---- waves 1-7: warm lists (2MB) + tbl (256KB) into this XCD's L2 ----
    const float4* lp = (const float4*)lists;
    float acc = 0.f;
    for (int i = tid - 64; i < 131072 + 16384; i += NT - 64) {
      float4 v = (i < 131072) ? lp[i] : tbl4[i - 131072];
      acc += v.x + v.y + v.z + v.w;
    }
    asm volatile("" :: "v"(acc));
  }
  __syncthreads();

  // ---- final flush: LDS -> global (order | flips | distances | ws) ----
  float* ord_f = tail;
  float* flp_f = tail + KE;
  float* dst_f = tail + 2 * KE;
#pragma unroll
  for (int k = 0; k < EPT; ++k) {
    int i = tid + k * NT;
    unsigned p = pk_lds[i];
    int w = (int)(p >> 1);
    int f = (int)(p & 1u);
    ord_f[i] = (float)w;
    flp_f[i] = (float)f;
    dst_f[i] = sqrtf(__uint_as_float(d2_lds[i]));
    ws_order[i] = w;
    ws_flip[i]  = f;
  }
}

extern "C" __global__ void __launch_bounds__(256)
gather_kernel(const float* __restrict__ edges, const int* __restrict__ ws_order,
              const int* __restrict__ ws_flip, float* __restrict__ out)
{
  int idx = blockIdx.x * 256 + threadIdx.x;   // < 25165824, fits int
  int i = idx / NPF;
  int f = idx - i * NPF;
  int o  = ws_order[i];
  int fl = ws_flip[i];
  int r = f / 3;
  int c = f - r * 3;
  int srcf = fl ? ((1023 - r) * 3 + c) : f;
  out[idx] = edges[o * NPF + srcf];
}

extern "C" void kernel_launch(void* const* d_in, const int* in_sizes, int n_in,
                              void* d_out, int out_size, void* d_ws, size_t ws_size,
                              hipStream_t stream) {
  (void)in_sizes; (void)n_in; (void)out_size;
  const float* edges = (const float*)d_in[0];
  float* out  = (float*)d_out;
  float* tail = out + (size_t)KE * NPF;        // order | flips | distances
  int* ws_order = (int*)d_ws;
  int* ws_flip  = ws_order + KE;

  size_t off_tbl = (size_t)2 * KE * sizeof(int);              //  64 KB
  size_t off_lst = off_tbl + (size_t)KE * 8 * sizeof(float);  // +256 KB
  size_t need_lst = off_lst + (size_t)2 * KE * KNN * sizeof(u64); // +2 MB

  float* tbl   = (ws_size >= off_lst) ? (float*)((char*)d_ws + off_tbl) : nullptr;
  u64*   lists = (ws_size >= need_lst && tbl) ? (u64*)((char*)d_ws + off_lst)
                                              : nullptr;

  if (tbl)
    hipLaunchKernelGGL(tbl_build_kernel, dim3(KE / 256), dim3(256), 0, stream,
                       edges, (float4*)tbl);
  if (lists)
    hipLaunchKernelGGL(knn_kernel, dim3(2 * KE / 64), dim3(64), 0, stream,
                       (const float4*)tbl, lists);
  hipLaunchKernelGGL(chain_kernel, dim3(1), dim3(NT), 0, stream,
                     edges, tail, ws_order, ws_flip, tbl, (const u64*)lists);
  hipLaunchKernelGGL(gather_kernel, dim3((KE * NPF) / 256), dim3(256), 0, stream,
                     edges, ws_order, ws_flip, out);
}

// Round 18
// 7087.512 us; speedup vs baseline: 2.3210x; 2.0076x over previous
//
#include <hip/hip_runtime.h>
#include <math.h>
#include <float.h>

#define KE 8192        // number of edges
#define NPF 3072       // floats per edge (1024 * 3)
#define NT 512         // threads (8 waves, all run the chain redundantly)
#define EPT 16         // edges per thread
#define NW  8          // waves
#define TOPK_N 10
#define KNN 16         // candidate list length
#define TAIL_T 7167    // main loop steps; live at tail start = 1024

typedef unsigned long long u64;
typedef float v2f __attribute__((ext_vector_type(2)));

#define GETP(arr, k) (((k) & 1) ? arr[(k) >> 1].y : arr[(k) >> 1].x)

#define DPPMIN(x, ctrl, rmask)                                              \
  do {                                                                      \
    unsigned _t = (unsigned)__builtin_amdgcn_update_dpp(                    \
        (int)0xFFFFFFFF, (int)(x), (ctrl), (rmask), 0xf, false);            \
    (x) = ((x) < _t) ? (x) : _t;                                            \
  } while (0)

// numpy-exact squared distance (no contraction) for DISCRETE decisions
__device__ __forceinline__ float dist2(float ax, float ay, float az,
                                       float bx, float by, float bz) {
#pragma clang fp contract(off)
  float dx = ax - bx, dy = ay - by, dz = az - bz;
  float s = (dx * dx + dy * dy) + dz * dz;
  return s;
}

// packed 2-edge squared distance, FMA form (argmin-safe; certified by bench)
__device__ __forceinline__ v2f dist2p(v2f cx, v2f cy, v2f cz,
                                      v2f px, v2f py, v2f pz) {
  v2f dx = px - cx, dy = py - cy, dz = pz - cz;
  return __builtin_elementwise_fma(dx, dx,
           __builtin_elementwise_fma(dy, dy, dz * dz));
}

// scalar twin of dist2p: IDENTICAL dataflow -> bitwise-identical values
__device__ __forceinline__ float dist2f(float cx, float cy, float cz,
                                        float px, float py, float pz) {
  float dx = px - cx, dy = py - cy, dz = pz - cz;
  return fmaf(dx, dx, fmaf(dy, dy, dz * dz));
}

__device__ __forceinline__ float dist3(float ax, float ay, float az,
                                       float bx, float by, float bz) {
  return sqrtf(dist2(ax, ay, az, bx, by, bz));
}

__device__ __forceinline__ u64 umin64(u64 a, u64 b) { return a < b ? a : b; }

// ---- build the compact 32B/edge endpoint table ----
extern "C" __global__ void __launch_bounds__(256)
tbl_build_kernel(const float* __restrict__ edges, float4* __restrict__ tbl4)
{
  int e = blockIdx.x * 256 + threadIdx.x;    // 8192 threads
  const float* p = edges + (size_t)e * NPF;
  float4 a, b;
  a.x = p[0]; a.y = p[1]; a.z = p[2]; a.w = p[NPF - 3];
  b.x = p[NPF - 2]; b.y = p[NPF - 1]; b.z = 0.f; b.w = 0.f;
  tbl4[(size_t)e * 2]     = a;
  tbl4[(size_t)e * 2 + 1] = b;
}

// ---- per-endpoint 16-NN edge lists, key = (d2bits<<32)|edge_idx ----
extern "C" __global__ void __launch_bounds__(64)
knn_kernel(const float4* __restrict__ tbl4, u64* __restrict__ lists)
{
  int q = blockIdx.x * 64 + threadIdx.x;     // 16384 threads (point id)
  float px, py, pz;
  {
    const float4* tp = tbl4 + (size_t)(q & (KE - 1)) * 2;
    float4 a = tp[0], b = tp[1];
    if (q < KE) { px = a.x; py = a.y; pz = a.z; }
    else        { px = a.w; py = b.x; pz = b.y; }
  }
  u64 kk[KNN];
#pragma unroll
  for (int i = 0; i < KNN; ++i) kk[i] = ~0ull;

  for (int e = 0; e < KE; ++e) {
    float4 a = tbl4[(size_t)e * 2];
    float4 b = tbl4[(size_t)e * 2 + 1];
    float d2s = dist2f(px, py, pz, a.x, a.y, a.z);
    float d2e = dist2f(px, py, pz, a.w, b.x, b.y);
    float v = fminf(d2s, d2e);
    u64 key = ((u64)__float_as_uint(v) << 32) | (unsigned)e;
    if (key < kk[KNN - 1]) {
      u64 c = key;
#pragma unroll
      for (int j = 0; j < KNN; ++j) {
        u64 lo = (kk[j] < c) ? kk[j] : c;
        c      = (kk[j] < c) ? c : kk[j];
        kk[j] = lo;
      }
    }
  }
  u64* lp = lists + (size_t)q * KNN;
#pragma unroll
  for (int i = 0; i < KNN; ++i) lp[i] = kk[i];
}

// R15-proven single-wave tail over the compacted 1024-entry LDS table.
__device__ void chain_tail(float& cxr, float& cyr, float& czr,
    unsigned* pk_lds, unsigned* d2_lds,
    const float4* s_ta, const float4* s_tb, int lane)
{
  constexpr int E = 16, NPT = 8;
  const int base = lane * E;
  v2f sxp[NPT], syp[NPT], szp[NPT], exp_[NPT], eyp[NPT], ezp[NPT];

#pragma unroll
  for (int e = 0; e < E; ++e) {
    float4 a = s_ta[base + e];
    float4 b = s_tb[base + e];
    if (e & 1) {
      sxp[e >> 1].y = a.x; syp[e >> 1].y = a.y; szp[e >> 1].y = a.z;
      exp_[e >> 1].y = a.w; eyp[e >> 1].y = b.x; ezp[e >> 1].y = b.y;
    } else {
      sxp[e >> 1].x = a.x; syp[e >> 1].x = a.y; szp[e >> 1].x = a.z;
      exp_[e >> 1].x = a.w; eyp[e >> 1].x = b.x; ezp[e >> 1].x = b.y;
    }
  }

  float cx = cxr, cy = cyr, cz = czr;

  for (int t = TAIL_T; t < KE - 1; ++t) {
    v2f cx2 = {cx, cx}, cy2 = {cy, cy}, cz2 = {cz, cz};
    float av0 = INFINITY, av1 = INFINITY, av2 = INFINITY, av3 = INFINITY;
    int   ai0 = 0, ai1 = 0, ai2 = 0, ai3 = 0;
#pragma unroll
    for (int p = 0; p < NPT; ++p) {
      v2f d2s = dist2p(cx2, cy2, cz2, sxp[p], syp[p], szp[p]);
      v2f d2e = dist2p(cx2, cy2, cz2, exp_[p], eyp[p], ezp[p]);
      v2f dm = __builtin_elementwise_min(d2s, d2e);
      int ix = base + 2 * p;
      int iy = base + 2 * p + 1;
      if ((p & 1) == 0) {
        if (dm.x < av0) { av0 = dm.x; ai0 = ix; }
        if (dm.y < av2) { av2 = dm.y; ai2 = iy; }
      } else {
        if (dm.x < av1) { av1 = dm.x; ai1 = ix; }
        if (dm.y < av3) { av3 = dm.y; ai3 = iy; }
      }
    }
    float mv = av0; int mi = ai0;
    if (av1 < mv || (av1 == mv && ai1 < mi)) { mv = av1; mi = ai1; }
    if (av2 < mv || (av2 == mv && ai2 < mi)) { mv = av2; mi = ai2; }
    if (av3 < mv || (av3 == mv && ai3 < mi)) { mv = av3; mi = ai3; }

    unsigned mvb = __float_as_uint(mv);
    unsigned x = mvb;
    DPPMIN(x, 0x111, 0xf);
    DPPMIN(x, 0x112, 0xf);
    DPPMIN(x, 0x114, 0xf);
    DPPMIN(x, 0x118, 0xf);
    DPPMIN(x, 0x142, 0xa);
    DPPMIN(x, 0x143, 0xc);
    unsigned wmin = (unsigned)__builtin_amdgcn_readlane((int)x, 63);

    u64 ball = __ballot(mvb == wmin);
    int win_lane = __ffsll(ball) - 1;
    int wpos = __builtin_amdgcn_readlane(mi, win_lane);

    float4 a = s_ta[wpos];
    float4 b = s_tb[wpos];
    int orig = __float_as_int(b.z);

    float da2 = dist2(cx, cy, cz, a.x, a.y, a.z);
    float db2 = dist2(cx, cy, cz, a.w, b.x, b.y);
    int fl = (sqrtf(da2) > sqrtf(db2)) ? 1 : 0;
    cx = fl ? a.x : a.w;
    cy = fl ? a.y : b.x;
    cz = fl ? a.z : b.y;

    if (lane == win_lane) {
      int e = wpos & (E - 1);
#pragma unroll
      for (int k = 0; k < NPT; ++k) {
        if ((e >> 1) == k) {
          if (e & 1) { sxp[k].y = INFINITY; exp_[k].y = INFINITY; }
          else       { sxp[k].x = INFINITY; exp_[k].x = INFINITY; }
        }
      }
      pk_lds[t + 1] = ((unsigned)orig << 1) | (unsigned)fl;
      d2_lds[t]     = wmin;
    }
  }

  cxr = cx; cyr = cy; czr = cz;
}

extern "C" __global__ void __launch_bounds__(NT, 1)
chain_kernel(const float* __restrict__ edges, float* __restrict__ tail,
             int* __restrict__ ws_order, int* __restrict__ ws_flip,
             float* __restrict__ tbl, const u64* __restrict__ lists)
{
  const int tid = threadIdx.x;
  const int lane = tid & 63;
  const int wid = tid >> 6;          // 0..7
  const int base = tid * EPT;
  const float4* tbl4 = (const float4*)tbl;

  __shared__ __align__(16) u64 kbuf[NW];
  __shared__ float  s_v[NW];
  __shared__ int    s_i[NW];
  __shared__ float  s_m1[NW], s_m2[NW];
  __shared__ unsigned pk_lds[KE];
  __shared__ unsigned d2_lds[KE];
  __shared__ unsigned bm[NW][KE / 32];          // per-WAVE private bitmaps
  __shared__ __align__(16) float4 s_ta[1024];   // tail coord table
  __shared__ __align__(16) float4 s_tb[1024];

  // zero this wave's private bitmap
  for (int i = lane; i < KE / 32; i += 64) bm[wid][i] = 0u;

  // ---- init: load endpoints into registers (512 threads x 16 edges) ----
  v2f sxp[EPT / 2], syp[EPT / 2], szp[EPT / 2];
  v2f exp_[EPT / 2], eyp[EPT / 2], ezp[EPT / 2];
#pragma unroll
  for (int e = 0; e < EPT; ++e) {
    const float* p = edges + (size_t)(base + e) * NPF;
    float a0 = p[0], a1 = p[1], a2 = p[2];
    float b0 = p[NPF - 3], b1 = p[NPF - 2], b2 = p[NPF - 1];
    if (e & 1) {
      sxp[e >> 1].y = a0; syp[e >> 1].y = a1; szp[e >> 1].y = a2;
      exp_[e >> 1].y = b0; eyp[e >> 1].y = b1; ezp[e >> 1].y = b2;
    } else {
      sxp[e >> 1].x = a0; syp[e >> 1].x = a1; szp[e >> 1].x = a2;
      exp_[e >> 1].x = b0; eyp[e >> 1].x = b1; ezp[e >> 1].x = b2;
    }
  }

  // ---- lengths; top-10; start_index = max index among them ----
  float len[EPT];
#pragma unroll
  for (int e = 0; e < EPT; ++e)
    len[e] = dist3(GETP(exp_, e), GETP(eyp, e), GETP(ezp, e),
                   GETP(sxp, e), GETP(syp, e), GETP(szp, e));

  unsigned tk = 0;
  int start_index = -1;
  for (int r = 0; r < TOPK_N; ++r) {
    float bv = -INFINITY; int bi = 0x7fffffff;
#pragma unroll
    for (int e = 0; e < EPT; ++e) {
      if ((tk >> e) & 1) continue;
      if (len[e] > bv) { bv = len[e]; bi = base + e; }
    }
    for (int m = 1; m < 64; m <<= 1) {
      float v2 = __shfl_xor(bv, m); int i2 = __shfl_xor(bi, m);
      if (v2 > bv || (v2 == bv && i2 < bi)) { bv = v2; bi = i2; }
    }
    if (lane == 0) { s_v[wid] = bv; s_i[wid] = bi; }
    __syncthreads();
    {
      float cv = s_v[lane & (NW - 1)]; int ci = s_i[lane & (NW - 1)];
      for (int m = 1; m < NW; m <<= 1) {
        float v2 = __shfl_xor(cv, m); int i2 = __shfl_xor(ci, m);
        if (v2 > cv || (v2 == cv && i2 < ci)) { cv = v2; ci = i2; }
      }
      int sel = ci;
      if ((sel / EPT) == tid) tk |= 1u << (sel & (EPT - 1));
      if (sel > start_index) start_index = sel;
    }
    __syncthreads();
  }

  // ---- s0 / e0: uniform global load ----
  float s0x, s0y, s0z, e0x, e0y, e0z;
  {
    const float* p = edges + (size_t)start_index * NPF;
    s0x = p[0];       s0y = p[1];       s0z = p[2];
    e0x = p[NPF - 3]; e0y = p[NPF - 2]; e0z = p[NPF - 1];
  }

  // ---- use_flip0 (numpy-exact; sqrt(min)==min(sqrt)) ----
  {
    float m1 = INFINITY, m2 = INFINITY;
#pragma unroll
    for (int e = 0; e < EPT; ++e) {
      int k = base + e;
      float a = dist2(s0x, s0y, s0z, GETP(sxp, e), GETP(syp, e), GETP(szp, e));
      float b = dist2(s0x, s0y, s0z, GETP(exp_, e), GETP(eyp, e), GETP(ezp, e));
      float c = dist2(e0x, e0y, e0z, GETP(sxp, e), GETP(syp, e), GETP(szp, e));
      float d = dist2(e0x, e0y, e0z, GETP(exp_, e), GETP(eyp, e), GETP(ezp, e));
      float v1 = fminf(a, b), v2 = fminf(c, d);
      if (k == start_index) { v1 = INFINITY; v2 = INFINITY; }
      m1 = fminf(m1, v1);
      m2 = fminf(m2, v2);
    }
    for (int m = 1; m < 64; m <<= 1) {
      m1 = fminf(m1, __shfl_xor(m1, m));
      m2 = fminf(m2, __shfl_xor(m2, m));
    }
    if (lane == 0) { s_m1[wid] = m1; s_m2[wid] = m2; }
  }
  __syncthreads();

  float cx, cy, cz, fx, fy, fz;
  int flip0;
  {
    float m1 = s_m1[lane & (NW - 1)], m2 = s_m2[lane & (NW - 1)];
    for (int m = 1; m < NW; m <<= 1) {
      m1 = fminf(m1, __shfl_xor(m1, m));
      m2 = fminf(m2, __shfl_xor(m2, m));
    }
    flip0 = (sqrtf(m1) < sqrtf(m2)) ? 1 : 0;
    cx = flip0 ? s0x : e0x;  cy = flip0 ? s0y : e0y;  cz = flip0 ? s0z : e0z;
    fx = flip0 ? e0x : s0x;  fy = flip0 ? e0y : s0y;  fz = flip0 ? e0z : s0z;
    if (tid == 0)
      pk_lds[0] = ((unsigned)start_index << 1) | (unsigned)flip0;
  }
  // each wave marks start edge in ITS bitmap
  if (lane == 0)
    bm[wid][start_index >> 5] |= 1u << (start_index & 31);

  // ---- warm lists (2MB) + tbl (256KB) into this XCD's L2 ----
  if (lists) {
    const float4* lp = (const float4*)lists;
    float acc = 0.f;
    for (int i = tid; i < 131072 + 16384; i += NT) {
      float4 v = (i < 131072) ? lp[i] : tbl4[i - 131072];
      acc += v.x + v.y + v.z + v.w;
    }
    asm volatile("" :: "v"(acc));
  }

  // owner of start edge: poison + clear alive
  unsigned alive = 0xFFFFu;
  if (tid == (start_index >> 4)) {
    int e = start_index & (EPT - 1);
#pragma unroll
    for (int k = 0; k < EPT / 2; ++k) {
      if ((e >> 1) == k) {
        if (e & 1) { sxp[k].y = INFINITY; exp_[k].y = INFINITY; }
        else       { sxp[k].x = INFINITY; exp_[k].x = INFINITY; }
      }
    }
    alive &= ~(1u << e);
  }
  __syncthreads();

  // bootstrap prefetch: candidate lists for both endpoints of start edge
  u64 pf = 0;
  const int win = (lane >> 4) & 3;
  if (lists) {
    if (win == 1) pf = lists[(size_t)start_index * KNN + (lane & 15)];
    else if (win == 2) pf = lists[(size_t)(start_index + KE) * KNN + (lane & 15)];
  }
  int fl_prev = flip0;

  // ========== main chain: hit path barrier-free, miss path R14 ==========
  for (int t = 0; t < TAIL_T; ++t) {
    int widx; unsigned wd2;
    bool hit = false;

    if (lists) {
      // every wave redundantly: select list, check OWN bitmap, ballot
      int src = (fl_prev ? 16 : 32) + (lane & 15);
      u64 kk = __shfl(pf, src);
      unsigned klo = (unsigned)kk, khi = (unsigned)(kk >> 32);
      unsigned w = bm[wid][klo >> 5];
      bool unused = (lane < 16) && !((w >> (klo & 31)) & 1);
      u64 ball = __ballot(unused);
      if (ball) {
        hit = true;                        // identical across waves
        int first = __ffsll(ball) - 1;
        widx = __builtin_amdgcn_readlane((int)klo, first);
        wd2  = (unsigned)__builtin_amdgcn_readlane((int)khi, first);
      }
    }

    if (!hit) {
      // uniform across waves -> barriers are safe. R14 scan machinery.
      v2f cx2 = {cx, cx}, cy2 = {cy, cy}, cz2 = {cz, cz};
      float av0 = INFINITY, av1 = INFINITY, av2 = INFINITY, av3 = INFINITY;
      int   ai0 = 0, ai1 = 0, ai2 = 0, ai3 = 0;
#pragma unroll
      for (int p = 0; p < EPT / 2; ++p) {
        v2f d2s = dist2p(cx2, cy2, cz2, sxp[p], syp[p], szp[p]);
        v2f d2e = dist2p(cx2, cy2, cz2, exp_[p], eyp[p], ezp[p]);
        v2f dm = __builtin_elementwise_min(d2s, d2e);
        int ix = base + 2 * p;
        int iy = base + 2 * p + 1;
        if ((p & 1) == 0) {
          if (dm.x < av0) { av0 = dm.x; ai0 = ix; }
          if (dm.y < av2) { av2 = dm.y; ai2 = iy; }
        } else {
          if (dm.x < av1) { av1 = dm.x; ai1 = ix; }
          if (dm.y < av3) { av3 = dm.y; ai3 = iy; }
        }
      }
      float mv = av0; int mi = ai0;
      if (av1 < mv || (av1 == mv && ai1 < mi)) { mv = av1; mi = ai1; }
      if (av2 < mv || (av2 == mv && ai2 < mi)) { mv = av2; mi = ai2; }
      if (av3 < mv || (av3 == mv && ai3 < mi)) { mv = av3; mi = ai3; }

      unsigned mvb = __float_as_uint(mv);
      unsigned x = mvb;
      DPPMIN(x, 0x111, 0xf);
      DPPMIN(x, 0x112, 0xf);
      DPPMIN(x, 0x114, 0xf);
      DPPMIN(x, 0x118, 0xf);
      DPPMIN(x, 0x142, 0xa);
      DPPMIN(x, 0x143, 0xc);
      unsigned wmin = (unsigned)__builtin_amdgcn_readlane((int)x, 63);
      u64 ball2 = __ballot(mvb == wmin);
      int win_lane = __ffsll(ball2) - 1;
      if (lane == win_lane)
        kbuf[wid] = ((u64)wmin << 32) | (unsigned)mi;
      __syncthreads();
      const ulonglong2* kp = (const ulonglong2*)&kbuf[0];
      ulonglong2 q0 = kp[0], q1 = kp[1], q2 = kp[2], q3 = kp[3];
      u64 kb = umin64(umin64(umin64(q0.x, q0.y), umin64(q1.x, q1.y)),
                      umin64(umin64(q2.x, q2.y), umin64(q3.x, q3.y)));
      widx = __builtin_amdgcn_readfirstlane((int)(kb & 0xFFFFFFFFu));
      wd2 = (unsigned)(kb >> 32);
      __syncthreads();               // protect kbuf reuse across wave skew
    }

    // prefetch next lists EARLY (both flip options of winner)
    if (lists) {
      if (win == 1) pf = lists[(size_t)widx * KNN + (lane & 15)];
      else if (win == 2) pf = lists[(size_t)(widx + KE) * KNN + (lane & 15)];
    }

    // winner coords (uniform, L2-warm) + exact flip
    float osx, osy, osz, oex, oey, oez;
    if (tbl4) {
      float4 a = tbl4[(size_t)widx * 2], b = tbl4[(size_t)widx * 2 + 1];
      osx = a.x; osy = a.y; osz = a.z; oex = a.w; oey = b.x; oez = b.y;
    } else {
      const float* wp = edges + (size_t)widx * NPF;
      osx = wp[0]; osy = wp[1]; osz = wp[2];
      oex = wp[NPF - 3]; oey = wp[NPF - 2]; oez = wp[NPF - 1];
    }
    float da2 = dist2(cx, cy, cz, osx, osy, osz);
    float db2 = dist2(cx, cy, cz, oex, oey, oez);
    int fl = (sqrtf(da2) > sqrtf(db2)) ? 1 : 0;
    cx = fl ? osx : oex;
    cy = fl ? osy : oey;
    cz = fl ? osz : oez;

    // bookkeeping: own-wave bitmap; owner poison+alive; wave0 outputs
    if (lane == 0) {
      bm[wid][widx >> 5] |= 1u << (widx & 31);
      if (wid == 0) {
        pk_lds[t + 1] = ((unsigned)widx << 1) | (unsigned)fl;
        d2_lds[t] = wd2;
      }
    }
    if (tid == (widx >> 4)) {
      int e = widx & (EPT - 1);
#pragma unroll
      for (int k = 0; k < EPT / 2; ++k) {
        if ((e >> 1) == k) {
          if (e & 1) { sxp[k].y = INFINITY; exp_[k].y = INFINITY; }
          else       { sxp[k].x = INFINITY; exp_[k].x = INFINITY; }
        }
      }
      alive &= ~(1u << e);
    }
    fl_prev = fl;
  }

  // ---- compacted LDS table (1024 live, ascending original index) ----
  __syncthreads();
  {
    int cnt = __popc(alive);
    int sc = cnt;
#pragma unroll
    for (int m = 1; m < 64; m <<= 1) {
      int o = __shfl_up(sc, m);
      if (lane >= m) sc += o;
    }
    if (lane == 63) s_i[wid] = sc;
    __syncthreads();
    int wbase = 0;
#pragma unroll
    for (int w = 0; w < NW; ++w)
      if (w < wid) wbase += s_i[w];
    int pos = wbase + sc - cnt;
#pragma unroll
    for (int e = 0; e < EPT; ++e) {
      if ((alive >> e) & 1) {
        float4 a, b;
        a.x = GETP(sxp, e); a.y = GETP(syp, e); a.z = GETP(szp, e);
        a.w = GETP(exp_, e);
        b.x = GETP(eyp, e); b.y = GETP(ezp, e);
        b.z = __int_as_float(base + e); b.w = 0.f;
        s_ta[pos] = a; s_tb[pos] = b; ++pos;
      }
    }
  }
  __syncthreads();

  // ---- tail: compacted single-wave scan (proven R15 structure) ----
  if (wid == 0) {
    chain_tail(cx, cy, cz, pk_lds, d2_lds, s_ta, s_tb, lane);
    if (lane == 0)
      d2_lds[KE - 1] = __float_as_uint(dist2(cx, cy, cz, fx, fy, fz));
  }
  __syncthreads();

  // ---- final flush: LDS -> global (order | flips | distances | ws) ----
  float* ord_f = tail;
  float* flp_f = tail + KE;
  float* dst_f = tail + 2 * KE;
#pragma unroll
  for (int k = 0; k < EPT; ++k) {
    int i = tid + k * NT;
    unsigned p = pk_lds[i];
    int w = (int)(p >> 1);
    int f = (int)(p & 1u);
    ord_f[i] = (float)w;
    flp_f[i] = (float)f;
    dst_f[i] = sqrtf(__uint_as_float(d2_lds[i]));
    ws_order[i] = w;
    ws_flip[i]  = f;
  }
}

extern "C" __global__ void __launch_bounds__(256)
gather_kernel(const float* __restrict__ edges, const int* __restrict__ ws_order,
              const int* __restrict__ ws_flip, float* __restrict__ out)
{
  int idx = blockIdx.x * 256 + threadIdx.x;   // < 25165824, fits int
  int i = idx / NPF;
  int f = idx - i * NPF;
  int o  = ws_order[i];
  int fl = ws_flip[i];
  int r = f / 3;
  int c = f - r * 3;
  int srcf = fl ? ((1023 - r) * 3 + c) : f;
  out[idx] = edges[o * NPF + srcf];
}

extern "C" void kernel_launch(void* const* d_in, const int* in_sizes, int n_in,
                              void* d_out, int out_size, void* d_ws, size_t ws_size,
                              hipStream_t stream) {
  (void)in_sizes; (void)n_in; (void)out_size;
  const float* edges = (const float*)d_in[0];
  float* out  = (float*)d_out;
  float* tail = out + (size_t)KE * NPF;        // order | flips | distances
  int* ws_order = (int*)d_ws;
  int* ws_flip  = ws_order + KE;

  size_t off_tbl = (size_t)2 * KE * sizeof(int);              //  64 KB
  size_t off_lst = off_tbl + (size_t)KE * 8 * sizeof(float);  // +256 KB
  size_t need_lst = off_lst + (size_t)2 * KE * KNN * sizeof(u64); // +2 MB

  float* tbl   = (ws_size >= off_lst) ? (float*)((char*)d_ws + off_tbl) : nullptr;
  u64*   lists = (ws_size >= need_lst && tbl) ? (u64*)((char*)d_ws + off_lst)
                                              : nullptr;

  if (tbl)
    hipLaunchKernelGGL(tbl_build_kernel, dim3(KE / 256), dim3(256), 0, stream,
                       edges, (float4*)tbl);
  if (lists)
    hipLaunchKernelGGL(knn_kernel, dim3(2 * KE / 64), dim3(64), 0, stream,
                       (const float4*)tbl, lists);
  hipLaunchKernelGGL(chain_kernel, dim3(1), dim3(NT), 0, stream,
                     edges, tail, ws_order, ws_flip, tbl, (const u64*)lists);
  hipLaunchKernelGGL(gather_kernel, dim3((KE * NPF) / 256), dim3(256), 0, stream,
                     edges, ws_order, ws_flip, out);
}